// Round 15
// baseline (400.391 us; speedup 1.0000x reference)
//
#include <hip/hip_runtime.h>
#include <hip/hip_bf16.h>
#include <stdint.h>

// DispersiveLoss: B=1024 rows, D=65536.
// R15: occupancy 2->4 blocks/CU. R14 (2 blocks, dbuf 64KB) left the LDS
// pipe at ~40% duty: 2 barrier-locked streams can't cover stage latency
// + dependency chains. Single 32KB buffer (A+B, BK=128) -> 4 blocks/CU;
// classic 2-barrier loop {stage; vmcnt(0); bar; read+MFMA; bar} with the
// stage stall covered by 3 other resident blocks (m97/m114 mechanism,
// proven at this tile size: m148 MX-fp8 1628 TF). Everything else = R14:
// MX-scaled 32x32x64 fp8 (scales=1.0), XOR-involution swizzle, upper-tri
// 128^2 tiles, XCD-grouped grid 1008 = 8 x 126.

#define NROWS 1024
#define KDIM  65536           // elements per row (= fp8 bytes per row)
#define NCHUNK 28             // K-chunks per tile
#define NTILE  36             // 8x8 upper-tri tiles
#define PARTN  1008           // 36 * 28

typedef __attribute__((ext_vector_type(4)))  int   i32x4;
typedef __attribute__((ext_vector_type(8)))  int   i32x8;
typedef __attribute__((ext_vector_type(16))) float f32x16;

#define AS1 __attribute__((address_space(1)))
#define AS3 __attribute__((address_space(3)))

// scales = 0x7F (E8M0 -> 2^0 = 1.0); cbsz=0/blgp=0 -> FP8 e4m3
#define MFMA_SC(a, b, c) \
  __builtin_amdgcn_mfma_scale_f32_32x32x64_f8f6f4((a), (b), (c), 0, 0, \
      0, 0x7F7F7F7F, 0, 0x7F7F7F7F)

// ---- fused: row sum-of-squares -> inv_norm, plus fp32 -> fp8 e4m3 cast ----
__global__ void k_prep(const float* __restrict__ z, uint32_t* __restrict__ zq,
                       float* __restrict__ inv_norm) {
  const int row = blockIdx.x;
  const float4* zr = (const float4*)(z + (size_t)row * KDIM);
  uint32_t* qr = zq + (size_t)row * (KDIM / 4);
  float ss = 0.f;
  for (int i = threadIdx.x; i < KDIM / 4; i += blockDim.x) {
    const float4 v = zr[i];
    ss += v.x * v.x + v.y * v.y + v.z * v.z + v.w * v.w;
    int p = __builtin_amdgcn_cvt_pk_fp8_f32(v.x, v.y, 0, false);   // bytes 0,1
    p     = __builtin_amdgcn_cvt_pk_fp8_f32(v.z, v.w, p, true);    // bytes 2,3
    qr[i] = (uint32_t)p;
  }
  for (int off = 32; off; off >>= 1) ss += __shfl_down(ss, off, 64);
  __shared__ float part[4];
  const int lane = threadIdx.x & 63, w = threadIdx.x >> 6;
  if (lane == 0) part[w] = ss;
  __syncthreads();
  if (threadIdx.x == 0) {
    const float t = part[0] + part[1] + part[2] + part[3];
    inv_norm[row] = 1.f / fmaxf(sqrtf(t), 1e-12f);
  }
}

// ---- 128^2 fp8 Gram via mfma_scale 32x32x64: BK=128, 32 KB single buffer ----
// LDS: A = 0..16K ; B = 16K..32K.  Panel swizzle: P = L ^ (((L>>7)&7)<<4).
__global__
__attribute__((amdgpu_flat_work_group_size(256, 256), amdgpu_waves_per_eu(4, 4)))
void k_gram8(const unsigned char* __restrict__ zb, float* __restrict__ pbuf) {
  extern __shared__ char smem[];
  const int tid  = threadIdx.x;
  const int lane = tid & 63;
  const int wid  = tid >> 6;     // 0..3
  const int wr   = wid >> 1;     // 0..1  (M half: 64 rows)
  const int wc   = wid & 1;      // 0..1  (N half: 64 cols)

  // XCD grouping: 1008 = 8 * 126; l = xcd*126 + idx (same-K tiles co-resident)
  const int d = blockIdx.x;
  const int l = (d & 7) * 126 + (d >> 3);
  const int kc   = l / NTILE;     // 0..27
  const int tile = l - kc * NTILE;
  // 512 K-tiles(128B) per tile: first 8 chunks take 19, rest 18
  const int kts = (kc < 8) ? kc * 19 : 152 + (kc - 8) * 18;
  const int cnt = (kc < 8) ? 19 : 18;
  const int pidx = l;

  // tile -> (tm, tn) in 8x8 upper-tri (row-major enumeration)
  int tm = 0, rr = tile;
  while (rr >= 8 - tm) { rr -= 8 - tm; ++tm; }
  const int tn = tm + rr;

  // staging per-thread constant (pre-swizzled source; linear LDS dest)
  const uint32_t Pt   = (uint32_t)tid * 16u;                 // 0..4080
  const uint32_t Lt   = Pt ^ (((Pt >> 7) & 7u) << 4);
  const uint32_t vOff = (Lt >> 7) * (uint32_t)KDIM + (Lt & 127u);

  // frag b128 address regs: addr = (fragrow0 + lane&31)*128 + sw(kk);
  // sw = (kk*64 + (lane>>5)*32) ^ ((lane&7)<<4); second b128 at ^16.
  const uint32_t mask = ((uint32_t)lane & 7u) << 4;
  const uint32_t rA = ((uint32_t)(wr * 64) + ((uint32_t)lane & 31u)) * 128u;
  const uint32_t rB = ((uint32_t)(wc * 64) + ((uint32_t)lane & 31u)) * 128u;
  const uint32_t h5 = ((uint32_t)lane >> 5) * 32u;
  uint32_t vA[2], vAx[2], vB[2], vBx[2];
#pragma unroll
  for (int kk = 0; kk < 2; kk++) {
    const uint32_t sw = ((uint32_t)(kk * 64) + h5) ^ mask;
    vA[kk]  = rA + sw;
    vAx[kk] = vA[kk] ^ 16u;
    vB[kk]  = 16384u + rB + sw;
    vBx[kk] = vB[kk] ^ 16u;
  }

  const char* zbC = (const char*)zb;
  const uint32_t gA = (uint32_t)(tm * 128) * (uint32_t)KDIM;
  const uint32_t gB = (uint32_t)(tn * 128) * (uint32_t)KDIM;

  // stage one 128x128B panel (16 KB): 4 x global_load_lds(16B)/thread
  auto stage_panel = [&](uint32_t gRowByte, uint32_t ldsBase, int ktAbs) {
    const uint32_t g0 = gRowByte + (uint32_t)ktAbs * 128u;
#pragma unroll
    for (int q = 0; q < 4; q++) {
      __builtin_amdgcn_global_load_lds(
          (const AS1 void*)(zbC + (g0 + (uint32_t)q * (32u * (uint32_t)KDIM) + vOff)),
          (AS3 void*)(smem + (ldsBase + (uint32_t)q * 4096u + Pt)), 16, 0, 0);
    }
  };

  // read one 32-row x 64-k fragment (two b128) at frag offset fi*4096
  auto rdf = [&](uint32_t base, uint32_t basex, int fi) -> i32x8 {
    const i32x4 lo = *(const i32x4*)(smem + (base  + (uint32_t)(fi * 4096)));
    const i32x4 hi = *(const i32x4*)(smem + (basex + (uint32_t)(fi * 4096)));
    return __builtin_shufflevector(lo, hi, 0, 1, 2, 3, 4, 5, 6, 7);
  };

  f32x16 acc[2][2];
#pragma unroll
  for (int m = 0; m < 2; m++)
#pragma unroll
    for (int n = 0; n < 2; n++)
#pragma unroll
      for (int r = 0; r < 16; r++) acc[m][n][r] = 0.f;

  i32x8 aF[2][2], bF[2][2];
  for (int T = 0; T < cnt; ++T) {
    // stage this K-tile (single buffer; prev iteration's reads fenced by bar#2)
    stage_panel(gA, 0u,      kts + T);
    stage_panel(gB, 16384u,  kts + T);
    asm volatile("s_waitcnt vmcnt(0)" ::: "memory");
    __builtin_amdgcn_s_barrier();          // #1: staged data visible to all
    asm volatile("" ::: "memory");

#pragma unroll
    for (int kk = 0; kk < 2; kk++) {
#pragma unroll
      for (int m = 0; m < 2; m++) aF[m][kk] = rdf(vA[kk], vAx[kk], m);
#pragma unroll
      for (int n = 0; n < 2; n++) bF[n][kk] = rdf(vB[kk], vBx[kk], n);
    }
    __builtin_amdgcn_s_setprio(1);
#pragma unroll
    for (int m = 0; m < 2; m++)
#pragma unroll
      for (int n = 0; n < 2; n++)
#pragma unroll
        for (int kk = 0; kk < 2; kk++)
          acc[m][n] = MFMA_SC(aF[m][kk], bF[n][kk], acc[m][n]);
    __builtin_amdgcn_s_setprio(0);
    __builtin_amdgcn_s_barrier();          // #2: all reads done -> overwritable
    asm volatile("" ::: "memory");
  }

  // epilogue: tile-local 128x128 partial (64 KB), non-atomic write
  // 32x32 C/D layout (m74/m101): col = lane&31, row = (r&3)+8*(r>>2)+4*(lane>>5)
  float* outp = pbuf + (size_t)pidx * 16384;
  const int r0 = wr * 64 + ((lane >> 5) << 2);
  const int c0 = wc * 64 + (lane & 31);
#pragma unroll
  for (int m = 0; m < 2; m++)
#pragma unroll
    for (int n = 0; n < 2; n++)
#pragma unroll
      for (int r = 0; r < 16; r++) {
        const int R = r0 + m * 32 + (r & 3) + ((r >> 2) << 3);
        const int C = c0 + n * 32;
        outp[(size_t)R * 128 + C] = acc[m][n][r];
      }
}

// helpers: tile id from (ti<=tj), 8x8 grid
__device__ __forceinline__ int tile_id(int ti, int tj) {
  return 8 * ti - ((ti * (ti - 1)) >> 1) + (tj - ti);
}

// ---- diag_n[i] = g[i][i] * inv_i^2 ----
__global__ void k_diag(const float* __restrict__ pbuf, const float* __restrict__ inv_norm,
                       float* __restrict__ diag) {
  const int i = blockIdx.x * 256 + threadIdx.x;
  const int ti = i >> 7;
  const int t = tile_id(ti, ti);
  const int off = (i & 127) * 129;
  float s = 0.f;
  for (int c = 0; c < NCHUNK; ++c)
    s += pbuf[(size_t)(c * NTILE + t) * 16384 + off];
  const float w = inv_norm[i];
  diag[i] = s * w * w;
}

// ---- accum = sum_{i<j} exp(-max(d_i + d_j - 2 g_ij inv_i inv_j, 0)) ----
__global__ void k_expsum(const float* __restrict__ pbuf, const float* __restrict__ inv_norm,
                         const float* __restrict__ diag, float* __restrict__ accum) {
  const int gid = blockIdx.x * 256 + threadIdx.x;
  const int e0 = gid * 4;
  const int i  = e0 >> 10;
  const int j0 = e0 & 1023;
  const int ti = i >> 7, tj = j0 >> 7;
  float s = 0.f;
  if (tj >= ti && j0 + 3 > i) {
    const int t = tile_id(ti, tj);
    const int off = (i & 127) * 128 + (j0 & 127);
    float gx = 0.f, gy = 0.f, gz = 0.f, gw = 0.f;
    for (int c = 0; c < NCHUNK; ++c) {
      const float4 v = *(const float4*)(pbuf + (size_t)(c * NTILE + t) * 16384 + off);
      gx += v.x; gy += v.y; gz += v.z; gw += v.w;
    }
    const float wi = inv_norm[i];
    const float di = diag[i];
    const float4 wj = *(const float4*)(inv_norm + j0);
    const float4 dj = *(const float4*)(diag + j0);
    float gn, d2;
    gn = gx * wi * wj.x; d2 = fmaxf(di + dj.x - 2.f * gn, 0.f); if (i < j0 + 0) s += expf(-d2);
    gn = gy * wi * wj.y; d2 = fmaxf(di + dj.y - 2.f * gn, 0.f); if (i < j0 + 1) s += expf(-d2);
    gn = gz * wi * wj.z; d2 = fmaxf(di + dj.z - 2.f * gn, 0.f); if (i < j0 + 2) s += expf(-d2);
    gn = gw * wi * wj.w; d2 = fmaxf(di + dj.w - 2.f * gn, 0.f); if (i < j0 + 3) s += expf(-d2);
  }
  for (int off = 32; off; off >>= 1) s += __shfl_down(s, off, 64);
  __shared__ float part[4];
  const int lane = threadIdx.x & 63, w = threadIdx.x >> 6;
  if (lane == 0) part[w] = s;
  __syncthreads();
  if (threadIdx.x == 0) atomicAdd(accum, part[0] + part[1] + part[2] + part[3]);
}

__global__ void k_final(const float* __restrict__ accum, float* __restrict__ out) {
  const float n_pairs = (float)NROWS * (float)(NROWS - 1) * 0.5f;
  out[0] = 0.25f * logf(accum[0] / n_pairs);
}

extern "C" void kernel_launch(void* const* d_in, const int* in_sizes, int n_in,
                              void* d_out, int out_size, void* d_ws, size_t ws_size,
                              hipStream_t stream) {
  const float* z = (const float*)d_in[0];
  float* out = (float*)d_out;
  char* ws = (char*)d_ws;

  // layout: inv_norm 4KB | diag 4KB | accum | ... | pbuf 63MB | zb(fp8) 64MB
  float*    inv_norm = (float*)(ws);
  float*    diag     = (float*)(ws + 4096);
  float*    accum    = (float*)(ws + 8192);
  float*    pbuf     = (float*)(ws + 65536);
  uint32_t* zq       = (uint32_t*)(ws + 65536 + (size_t)PARTN * 16384 * sizeof(float));

  hipMemsetAsync(accum, 0, sizeof(float), stream);

  k_prep<<<NROWS, 256, 0, stream>>>(z, zq, inv_norm);

  hipFuncSetAttribute(reinterpret_cast<const void*>(&k_gram8),
                      hipFuncAttributeMaxDynamicSharedMemorySize, 32768);
  k_gram8<<<PARTN, 256, 32768, stream>>>((const unsigned char*)zq, pbuf);

  k_diag<<<NROWS / 256, 256, 0, stream>>>(pbuf, inv_norm, diag);
  k_expsum<<<(NROWS * NROWS / 4) / 256, 256, 0, stream>>>(pbuf, inv_norm, diag, accum);
  k_final<<<1, 1, 0, stream>>>(accum, out);
}

// Round 16
// 163.130 us; speedup vs baseline: 2.4544x; 2.4544x over previous
//
#include <hip/hip_runtime.h>
#include <hip/hip_bf16.h>
#include <stdint.h>

// DispersiveLoss: B=1024 rows, D=65536.
// R16: R15 (4 blocks/CU, 32KB single-buf, 2-barrier loop) with the spill
// fixed. R15's waves_per_eu(4,4) budget = 128 regs/wave; acc(64,AGPR) +
// ALL-8-frags-live(64 VGPR) + addr blew it -> 550MB scratch traffic.
// Fix: kk-split inner loop -- only 4 frags (32 VGPR) live at a time;
// live set = 64 acc + 32 frag + ~20 addr <= 128. Everything else = R15:
// MX-scaled 32x32x64 fp8 (scales=1.0), XOR-involution swizzle, upper-tri
// 128^2 tiles, XCD-grouped grid 1008 = 8 x 126.

#define NROWS 1024
#define KDIM  65536           // elements per row (= fp8 bytes per row)
#define NCHUNK 28             // K-chunks per tile
#define NTILE  36             // 8x8 upper-tri tiles
#define PARTN  1008           // 36 * 28

typedef __attribute__((ext_vector_type(4)))  int   i32x4;
typedef __attribute__((ext_vector_type(8)))  int   i32x8;
typedef __attribute__((ext_vector_type(16))) float f32x16;

#define AS1 __attribute__((address_space(1)))
#define AS3 __attribute__((address_space(3)))

// scales = 0x7F (E8M0 -> 2^0 = 1.0); cbsz=0/blgp=0 -> FP8 e4m3
#define MFMA_SC(a, b, c) \
  __builtin_amdgcn_mfma_scale_f32_32x32x64_f8f6f4((a), (b), (c), 0, 0, \
      0, 0x7F7F7F7F, 0, 0x7F7F7F7F)

// ---- fused: row sum-of-squares -> inv_norm, plus fp32 -> fp8 e4m3 cast ----
__global__ void k_prep(const float* __restrict__ z, uint32_t* __restrict__ zq,
                       float* __restrict__ inv_norm) {
  const int row = blockIdx.x;
  const float4* zr = (const float4*)(z + (size_t)row * KDIM);
  uint32_t* qr = zq + (size_t)row * (KDIM / 4);
  float ss = 0.f;
  for (int i = threadIdx.x; i < KDIM / 4; i += blockDim.x) {
    const float4 v = zr[i];
    ss += v.x * v.x + v.y * v.y + v.z * v.z + v.w * v.w;
    int p = __builtin_amdgcn_cvt_pk_fp8_f32(v.x, v.y, 0, false);   // bytes 0,1
    p     = __builtin_amdgcn_cvt_pk_fp8_f32(v.z, v.w, p, true);    // bytes 2,3
    qr[i] = (uint32_t)p;
  }
  for (int off = 32; off; off >>= 1) ss += __shfl_down(ss, off, 64);
  __shared__ float part[4];
  const int lane = threadIdx.x & 63, w = threadIdx.x >> 6;
  if (lane == 0) part[w] = ss;
  __syncthreads();
  if (threadIdx.x == 0) {
    const float t = part[0] + part[1] + part[2] + part[3];
    inv_norm[row] = 1.f / fmaxf(sqrtf(t), 1e-12f);
  }
}

// ---- 128^2 fp8 Gram via mfma_scale 32x32x64: BK=128, 32 KB single buffer ----
// LDS: A = 0..16K ; B = 16K..32K.  Panel swizzle: P = L ^ (((L>>7)&7)<<4).
__global__
__attribute__((amdgpu_flat_work_group_size(256, 256), amdgpu_waves_per_eu(4, 4)))
void k_gram8(const unsigned char* __restrict__ zb, float* __restrict__ pbuf) {
  extern __shared__ char smem[];
  const int tid  = threadIdx.x;
  const int lane = tid & 63;
  const int wid  = tid >> 6;     // 0..3
  const int wr   = wid >> 1;     // 0..1  (M half: 64 rows)
  const int wc   = wid & 1;      // 0..1  (N half: 64 cols)

  // XCD grouping: 1008 = 8 * 126; l = xcd*126 + idx (same-K tiles co-resident)
  const int d = blockIdx.x;
  const int l = (d & 7) * 126 + (d >> 3);
  const int kc   = l / NTILE;     // 0..27
  const int tile = l - kc * NTILE;
  // 512 K-tiles(128B) per tile: first 8 chunks take 19, rest 18
  const int kts = (kc < 8) ? kc * 19 : 152 + (kc - 8) * 18;
  const int cnt = (kc < 8) ? 19 : 18;
  const int pidx = l;

  // tile -> (tm, tn) in 8x8 upper-tri (row-major enumeration)
  int tm = 0, rr = tile;
  while (rr >= 8 - tm) { rr -= 8 - tm; ++tm; }
  const int tn = tm + rr;

  // staging per-thread constant (pre-swizzled source; linear LDS dest)
  const uint32_t Pt   = (uint32_t)tid * 16u;                 // 0..4080
  const uint32_t Lt   = Pt ^ (((Pt >> 7) & 7u) << 4);
  const uint32_t vOff = (Lt >> 7) * (uint32_t)KDIM + (Lt & 127u);

  // frag b128 address regs: addr = (fragrow0 + lane&31)*128 + sw(kk);
  // sw = (kk*64 + (lane>>5)*32) ^ ((lane&7)<<4); second b128 at ^16.
  const uint32_t mask = ((uint32_t)lane & 7u) << 4;
  const uint32_t rA = ((uint32_t)(wr * 64) + ((uint32_t)lane & 31u)) * 128u;
  const uint32_t rB = ((uint32_t)(wc * 64) + ((uint32_t)lane & 31u)) * 128u;
  const uint32_t h5 = ((uint32_t)lane >> 5) * 32u;
  uint32_t vA[2], vAx[2], vB[2], vBx[2];
#pragma unroll
  for (int kk = 0; kk < 2; kk++) {
    const uint32_t sw = ((uint32_t)(kk * 64) + h5) ^ mask;
    vA[kk]  = rA + sw;
    vAx[kk] = vA[kk] ^ 16u;
    vB[kk]  = 16384u + rB + sw;
    vBx[kk] = vB[kk] ^ 16u;
  }

  const char* zbC = (const char*)zb;
  const uint32_t gA = (uint32_t)(tm * 128) * (uint32_t)KDIM;
  const uint32_t gB = (uint32_t)(tn * 128) * (uint32_t)KDIM;

  // stage one 128x128B panel (16 KB): 4 x global_load_lds(16B)/thread
  auto stage_panel = [&](uint32_t gRowByte, uint32_t ldsBase, int ktAbs) {
    const uint32_t g0 = gRowByte + (uint32_t)ktAbs * 128u;
#pragma unroll
    for (int q = 0; q < 4; q++) {
      __builtin_amdgcn_global_load_lds(
          (const AS1 void*)(zbC + (g0 + (uint32_t)q * (32u * (uint32_t)KDIM) + vOff)),
          (AS3 void*)(smem + (ldsBase + (uint32_t)q * 4096u + Pt)), 16, 0, 0);
    }
  };

  // read one 32-row x 64-k fragment (two b128) at frag offset fi*4096
  auto rdf = [&](uint32_t base, uint32_t basex, int fi) -> i32x8 {
    const i32x4 lo = *(const i32x4*)(smem + (base  + (uint32_t)(fi * 4096)));
    const i32x4 hi = *(const i32x4*)(smem + (basex + (uint32_t)(fi * 4096)));
    return __builtin_shufflevector(lo, hi, 0, 1, 2, 3, 4, 5, 6, 7);
  };

  f32x16 acc[2][2];
#pragma unroll
  for (int m = 0; m < 2; m++)
#pragma unroll
    for (int n = 0; n < 2; n++)
#pragma unroll
      for (int r = 0; r < 16; r++) acc[m][n][r] = 0.f;

  for (int T = 0; T < cnt; ++T) {
    // stage this K-tile (single buffer; prev reads fenced by barrier #2)
    stage_panel(gA, 0u,      kts + T);
    stage_panel(gB, 16384u,  kts + T);
    asm volatile("s_waitcnt vmcnt(0)" ::: "memory");
    __builtin_amdgcn_s_barrier();          // #1: staged data visible
    asm volatile("" ::: "memory");

    // kk-split: only 4 frags (32 VGPR) live at a time -> no spill at the
    // 128-reg/wave budget of 4 waves/EU.
#pragma unroll
    for (int kk = 0; kk < 2; kk++) {
      i32x8 a0 = rdf(vA[kk], vAx[kk], 0);
      i32x8 a1 = rdf(vA[kk], vAx[kk], 1);
      i32x8 b0 = rdf(vB[kk], vBx[kk], 0);
      i32x8 b1 = rdf(vB[kk], vBx[kk], 1);
      __builtin_amdgcn_s_setprio(1);
      acc[0][0] = MFMA_SC(a0, b0, acc[0][0]);
      acc[0][1] = MFMA_SC(a0, b1, acc[0][1]);
      acc[1][0] = MFMA_SC(a1, b0, acc[1][0]);
      acc[1][1] = MFMA_SC(a1, b1, acc[1][1]);
      __builtin_amdgcn_s_setprio(0);
    }
    __builtin_amdgcn_s_barrier();          // #2: all reads done -> overwritable
    asm volatile("" ::: "memory");
  }

  // epilogue: tile-local 128x128 partial (64 KB), non-atomic write
  // 32x32 C/D layout (m74/m101): col = lane&31, row = (r&3)+8*(r>>2)+4*(lane>>5)
  float* outp = pbuf + (size_t)pidx * 16384;
  const int r0 = wr * 64 + ((lane >> 5) << 2);
  const int c0 = wc * 64 + (lane & 31);
#pragma unroll
  for (int m = 0; m < 2; m++)
#pragma unroll
    for (int n = 0; n < 2; n++)
#pragma unroll
      for (int r = 0; r < 16; r++) {
        const int R = r0 + m * 32 + (r & 3) + ((r >> 2) << 3);
        const int C = c0 + n * 32;
        outp[(size_t)R * 128 + C] = acc[m][n][r];
      }
}

// helpers: tile id from (ti<=tj), 8x8 grid
__device__ __forceinline__ int tile_id(int ti, int tj) {
  return 8 * ti - ((ti * (ti - 1)) >> 1) + (tj - ti);
}

// ---- diag_n[i] = g[i][i] * inv_i^2 ----
__global__ void k_diag(const float* __restrict__ pbuf, const float* __restrict__ inv_norm,
                       float* __restrict__ diag) {
  const int i = blockIdx.x * 256 + threadIdx.x;
  const int ti = i >> 7;
  const int t = tile_id(ti, ti);
  const int off = (i & 127) * 129;
  float s = 0.f;
  for (int c = 0; c < NCHUNK; ++c)
    s += pbuf[(size_t)(c * NTILE + t) * 16384 + off];
  const float w = inv_norm[i];
  diag[i] = s * w * w;
}

// ---- accum = sum_{i<j} exp(-max(d_i + d_j - 2 g_ij inv_i inv_j, 0)) ----
__global__ void k_expsum(const float* __restrict__ pbuf, const float* __restrict__ inv_norm,
                         const float* __restrict__ diag, float* __restrict__ accum) {
  const int gid = blockIdx.x * 256 + threadIdx.x;
  const int e0 = gid * 4;
  const int i  = e0 >> 10;
  const int j0 = e0 & 1023;
  const int ti = i >> 7, tj = j0 >> 7;
  float s = 0.f;
  if (tj >= ti && j0 + 3 > i) {
    const int t = tile_id(ti, tj);
    const int off = (i & 127) * 128 + (j0 & 127);
    float gx = 0.f, gy = 0.f, gz = 0.f, gw = 0.f;
    for (int c = 0; c < NCHUNK; ++c) {
      const float4 v = *(const float4*)(pbuf + (size_t)(c * NTILE + t) * 16384 + off);
      gx += v.x; gy += v.y; gz += v.z; gw += v.w;
    }
    const float wi = inv_norm[i];
    const float di = diag[i];
    const float4 wj = *(const float4*)(inv_norm + j0);
    const float4 dj = *(const float4*)(diag + j0);
    float gn, d2;
    gn = gx * wi * wj.x; d2 = fmaxf(di + dj.x - 2.f * gn, 0.f); if (i < j0 + 0) s += expf(-d2);
    gn = gy * wi * wj.y; d2 = fmaxf(di + dj.y - 2.f * gn, 0.f); if (i < j0 + 1) s += expf(-d2);
    gn = gz * wi * wj.z; d2 = fmaxf(di + dj.z - 2.f * gn, 0.f); if (i < j0 + 2) s += expf(-d2);
    gn = gw * wi * wj.w; d2 = fmaxf(di + dj.w - 2.f * gn, 0.f); if (i < j0 + 3) s += expf(-d2);
  }
  for (int off = 32; off; off >>= 1) s += __shfl_down(s, off, 64);
  __shared__ float part[4];
  const int lane = threadIdx.x & 63, w = threadIdx.x >> 6;
  if (lane == 0) part[w] = s;
  __syncthreads();
  if (threadIdx.x == 0) atomicAdd(accum, part[0] + part[1] + part[2] + part[3]);
}

__global__ void k_final(const float* __restrict__ accum, float* __restrict__ out) {
  const float n_pairs = (float)NROWS * (float)(NROWS - 1) * 0.5f;
  out[0] = 0.25f * logf(accum[0] / n_pairs);
}

extern "C" void kernel_launch(void* const* d_in, const int* in_sizes, int n_in,
                              void* d_out, int out_size, void* d_ws, size_t ws_size,
                              hipStream_t stream) {
  const float* z = (const float*)d_in[0];
  float* out = (float*)d_out;
  char* ws = (char*)d_ws;

  // layout: inv_norm 4KB | diag 4KB | accum | ... | pbuf 63MB | zb(fp8) 64MB
  float*    inv_norm = (float*)(ws);
  float*    diag     = (float*)(ws + 4096);
  float*    accum    = (float*)(ws + 8192);
  float*    pbuf     = (float*)(ws + 65536);
  uint32_t* zq       = (uint32_t*)(ws + 65536 + (size_t)PARTN * 16384 * sizeof(float));

  hipMemsetAsync(accum, 0, sizeof(float), stream);

  k_prep<<<NROWS, 256, 0, stream>>>(z, zq, inv_norm);

  hipFuncSetAttribute(reinterpret_cast<const void*>(&k_gram8),
                      hipFuncAttributeMaxDynamicSharedMemorySize, 32768);
  k_gram8<<<PARTN, 256, 32768, stream>>>((const unsigned char*)zq, pbuf);

  k_diag<<<NROWS / 256, 256, 0, stream>>>(pbuf, inv_norm, diag);
  k_expsum<<<(NROWS * NROWS / 4) / 256, 256, 0, stream>>>(pbuf, inv_norm, diag, accum);
  k_final<<<1, 1, 0, stream>>>(accum, out);
}

// Round 17
// 139.100 us; speedup vs baseline: 2.8784x; 1.1728x over previous
//
#include <hip/hip_runtime.h>
#include <hip/hip_bf16.h>
#include <stdint.h>

// DispersiveLoss: B=1024 rows, D=65536.
// R17: R14 structure (128^2 tiles, 64KB LDS dbuf, single-barrier loop,
// MX-fp8 32x32x64, 2 blocks/CU) with 512-thr / 8-wave blocks -> 4
// waves/SIMD (R14 had 2: ~1600 cyc/iter of unhidden ds_read/stage
// latency). Wave output 32x64 (acc 32 AGPR); kk-split keeps live set
// ~90 regs under the 128-reg waves_per_eu(4,4) budget. diag==1.0
// exactly (normalized rows) -> k_diag deleted.

#define NROWS 1024
#define KDIM  65536           // elements per row (= fp8 bytes per row)
#define NCHUNK 14             // K-chunks per tile
#define NTILE  36             // 8x8 upper-tri tiles
#define PARTN  504            // 36 * 14

typedef __attribute__((ext_vector_type(4)))  int   i32x4;
typedef __attribute__((ext_vector_type(8)))  int   i32x8;
typedef __attribute__((ext_vector_type(16))) float f32x16;

#define AS1 __attribute__((address_space(1)))
#define AS3 __attribute__((address_space(3)))

// scales = 0x7F (E8M0 -> 2^0 = 1.0); cbsz=0/blgp=0 -> FP8 e4m3
#define MFMA_SC(a, b, c) \
  __builtin_amdgcn_mfma_scale_f32_32x32x64_f8f6f4((a), (b), (c), 0, 0, \
      0, 0x7F7F7F7F, 0, 0x7F7F7F7F)

// ---- fused: row sum-of-squares -> inv_norm, plus fp32 -> fp8 e4m3 cast ----
__global__ void k_prep(const float* __restrict__ z, uint32_t* __restrict__ zq,
                       float* __restrict__ inv_norm) {
  const int row = blockIdx.x;
  const float4* zr = (const float4*)(z + (size_t)row * KDIM);
  uint32_t* qr = zq + (size_t)row * (KDIM / 4);
  float ss = 0.f;
  for (int i = threadIdx.x; i < KDIM / 4; i += blockDim.x) {
    const float4 v = zr[i];
    ss += v.x * v.x + v.y * v.y + v.z * v.z + v.w * v.w;
    int p = __builtin_amdgcn_cvt_pk_fp8_f32(v.x, v.y, 0, false);   // bytes 0,1
    p     = __builtin_amdgcn_cvt_pk_fp8_f32(v.z, v.w, p, true);    // bytes 2,3
    qr[i] = (uint32_t)p;
  }
  for (int off = 32; off; off >>= 1) ss += __shfl_down(ss, off, 64);
  __shared__ float part[4];
  const int lane = threadIdx.x & 63, w = threadIdx.x >> 6;
  if (lane == 0) part[w] = ss;
  __syncthreads();
  if (threadIdx.x == 0) {
    const float t = part[0] + part[1] + part[2] + part[3];
    inv_norm[row] = 1.f / fmaxf(sqrtf(t), 1e-12f);
  }
}

// ---- 128^2 fp8 Gram via mfma_scale 32x32x64: BK=128, 64 KB LDS dbuf ----
// LDS: A[buf] = buf*16384 ; B[buf] = 32768 + buf*16384 (16 KB panels).
// Swizzle within a panel (128 rows x 128 B): P = L ^ (((L>>7)&7)<<4).
__global__
__attribute__((amdgpu_flat_work_group_size(512, 512), amdgpu_waves_per_eu(4, 4)))
void k_gram8(const unsigned char* __restrict__ zb, float* __restrict__ pbuf) {
  extern __shared__ char smem[];
  const int tid  = threadIdx.x;
  const int lane = tid & 63;
  const int wid  = tid >> 6;     // 0..7
  const int wr   = wid >> 1;     // 0..3  (M quarter: 32 rows)
  const int wc   = wid & 1;      // 0..1  (N half: 64 cols)

  // XCD grouping: 504 = 8 * 63; l = xcd*63 + idx (same-K tiles co-resident)
  const int d = blockIdx.x;
  const int l = (d & 7) * 63 + (d >> 3);
  const int kc   = l / NTILE;     // 0..13
  const int tile = l - kc * NTILE;
  // 512 K-tiles(128B) per tile: first 8 chunks take 37, rest 36
  const int kts = (kc < 8) ? kc * 37 : 296 + (kc - 8) * 36;
  const int cnt = (kc < 8) ? 37 : 36;
  const int pidx = l;

  // tile -> (tm, tn) in 8x8 upper-tri (row-major enumeration)
  int tm = 0, rr = tile;
  while (rr >= 8 - tm) { rr -= 8 - tm; ++tm; }
  const int tn = tm + rr;

  // staging per-thread constant (pre-swizzled source; linear LDS dest)
  const uint32_t Pt   = (uint32_t)tid * 16u;                 // 0..8176
  const uint32_t Lt   = Pt ^ (((Pt >> 7) & 7u) << 4);
  const uint32_t vOff = (Lt >> 7) * (uint32_t)KDIM + (Lt & 127u);

  // frag b128 address regs: addr = (fragrow0 + lane&31)*128 + sw(kk);
  // sw = (kk*64 + (lane>>5)*32) ^ ((lane&7)<<4); second b128 at ^16.
  const uint32_t mask = ((uint32_t)lane & 7u) << 4;
  const uint32_t rA = ((uint32_t)(wr * 32) + ((uint32_t)lane & 31u)) * 128u;
  const uint32_t rB = ((uint32_t)(wc * 64) + ((uint32_t)lane & 31u)) * 128u;
  const uint32_t h5 = ((uint32_t)lane >> 5) * 32u;
  uint32_t vA[2], vAx[2], vB[2], vBx[2];
#pragma unroll
  for (int kk = 0; kk < 2; kk++) {
    const uint32_t sw = ((uint32_t)(kk * 64) + h5) ^ mask;
    vA[kk]  = rA + sw;
    vAx[kk] = vA[kk] ^ 16u;
    vB[kk]  = 32768u + rB + sw;
    vBx[kk] = vB[kk] ^ 16u;
  }

  const char* zbC = (const char*)zb;
  const uint32_t gA = (uint32_t)(tm * 128) * (uint32_t)KDIM;
  const uint32_t gB = (uint32_t)(tn * 128) * (uint32_t)KDIM;

  // stage one 128x128B panel (16 KB): 2 x global_load_lds(16B)/thread
  auto stage_panel = [&](uint32_t gRowByte, uint32_t ldsBase, int ktAbs) {
    const uint32_t g0 = gRowByte + (uint32_t)ktAbs * 128u;
#pragma unroll
    for (int q = 0; q < 2; q++) {
      __builtin_amdgcn_global_load_lds(
          (const AS1 void*)(zbC + (g0 + (uint32_t)q * (64u * (uint32_t)KDIM) + vOff)),
          (AS3 void*)(smem + (ldsBase + (uint32_t)q * 8192u + Pt)), 16, 0, 0);
    }
  };

  // read one 32-row x 64-k fragment (two b128) at frag offset fi*4096
  auto rdf = [&](uint32_t base, uint32_t basex, int fi) -> i32x8 {
    const i32x4 lo = *(const i32x4*)(smem + (base  + (uint32_t)(fi * 4096)));
    const i32x4 hi = *(const i32x4*)(smem + (basex + (uint32_t)(fi * 4096)));
    return __builtin_shufflevector(lo, hi, 0, 1, 2, 3, 4, 5, 6, 7);
  };

  f32x16 acc[2];   // [ni]: wave output 32 rows x 64 cols
#pragma unroll
  for (int n = 0; n < 2; n++)
#pragma unroll
    for (int r = 0; r < 16; r++) acc[n][r] = 0.f;

  // prologue: A(kts), B(kts) -> buf0
  stage_panel(gA, 0u,      kts);
  stage_panel(gB, 32768u,  kts);
  asm volatile("s_waitcnt vmcnt(0)" ::: "memory");
  __builtin_amdgcn_s_barrier();
  asm volatile("" ::: "memory");

  for (int T = 0; T < cnt; ++T) {
    const uint32_t idle = (uint32_t)((T + 1) & 1) * 16384u;
    const bool st = (T + 1 < cnt);

    // stage next tile into idle buf (disjoint from cur -> no race)
    if (st) {
      stage_panel(gA, idle,           kts + T + 1);
      stage_panel(gB, 32768u + idle,  kts + T + 1);
    }
    // kk-split reads+MFMA in one region: compiler interleaves counted
    // lgkmcnt; 4 waves/SIMD fill the dependency gaps.
#pragma unroll
    for (int kk = 0; kk < 2; kk++) {
      i32x8 a0 = rdf(vA[kk], vAx[kk], 0);
      i32x8 b0 = rdf(vB[kk], vBx[kk], 0);
      i32x8 b1 = rdf(vB[kk], vBx[kk], 1);
      __builtin_amdgcn_s_setprio(1);
      acc[0] = MFMA_SC(a0, b0, acc[0]);
      acc[1] = MFMA_SC(a0, b1, acc[1]);
      __builtin_amdgcn_s_setprio(0);
    }
    // drain T+1's loads so next iteration may read them
    asm volatile("s_waitcnt vmcnt(0)" ::: "memory");
    __builtin_amdgcn_s_barrier();
    asm volatile("" ::: "memory");
#pragma unroll
    for (int kk = 0; kk < 2; kk++) {
      vA[kk] ^= 16384u; vAx[kk] ^= 16384u; vB[kk] ^= 16384u; vBx[kk] ^= 16384u;
    }
  }

  // epilogue: tile-local 128x128 partial (64 KB), non-atomic write
  // 32x32 C/D layout (m74/m101): col = lane&31, row = (r&3)+8*(r>>2)+4*(lane>>5)
  float* outp = pbuf + (size_t)pidx * 16384;
  const int r0 = wr * 32 + ((lane >> 5) << 2);
  const int c0 = wc * 64 + (lane & 31);
#pragma unroll
  for (int n = 0; n < 2; n++)
#pragma unroll
    for (int r = 0; r < 16; r++) {
      const int R = r0 + (r & 3) + ((r >> 2) << 3);
      const int C = c0 + n * 32;
      outp[(size_t)R * 128 + C] = acc[n][r];
    }
}

// helpers: tile id from (ti<=tj), 8x8 grid
__device__ __forceinline__ int tile_id(int ti, int tj) {
  return 8 * ti - ((ti * (ti - 1)) >> 1) + (tj - ti);
}

// ---- accum = sum_{i<j} exp(-max(2 - 2 g_ij inv_i inv_j, 0)) ----
// diag_n == 1.0 exactly (reference normalizes rows; sq_i = 1 +- fp32 eps).
__global__ void k_expsum(const float* __restrict__ pbuf, const float* __restrict__ inv_norm,
                         float* __restrict__ accum) {
  const int gid = blockIdx.x * 256 + threadIdx.x;
  const int e0 = gid * 4;
  const int i  = e0 >> 10;
  const int j0 = e0 & 1023;
  const int ti = i >> 7, tj = j0 >> 7;
  float s = 0.f;
  if (tj >= ti && j0 + 3 > i) {
    const int t = tile_id(ti, tj);
    const int off = (i & 127) * 128 + (j0 & 127);
    float gx = 0.f, gy = 0.f, gz = 0.f, gw = 0.f;
    for (int c = 0; c < NCHUNK; ++c) {
      const float4 v = *(const float4*)(pbuf + (size_t)(c * NTILE + t) * 16384 + off);
      gx += v.x; gy += v.y; gz += v.z; gw += v.w;
    }
    const float wi = inv_norm[i];
    const float4 wj = *(const float4*)(inv_norm + j0);
    float gn, d2;
    gn = gx * wi * wj.x; d2 = fmaxf(2.f - 2.f * gn, 0.f); if (i < j0 + 0) s += expf(-d2);
    gn = gy * wi * wj.y; d2 = fmaxf(2.f - 2.f * gn, 0.f); if (i < j0 + 1) s += expf(-d2);
    gn = gz * wi * wj.z; d2 = fmaxf(2.f - 2.f * gn, 0.f); if (i < j0 + 2) s += expf(-d2);
    gn = gw * wi * wj.w; d2 = fmaxf(2.f - 2.f * gn, 0.f); if (i < j0 + 3) s += expf(-d2);
  }
  for (int off = 32; off; off >>= 1) s += __shfl_down(s, off, 64);
  __shared__ float part[4];
  const int lane = threadIdx.x & 63, w = threadIdx.x >> 6;
  if (lane == 0) part[w] = s;
  __syncthreads();
  if (threadIdx.x == 0) atomicAdd(accum, part[0] + part[1] + part[2] + part[3]);
}

__global__ void k_final(const float* __restrict__ accum, float* __restrict__ out) {
  const float n_pairs = (float)NROWS * (float)(NROWS - 1) * 0.5f;
  out[0] = 0.25f * logf(accum[0] / n_pairs);
}

extern "C" void kernel_launch(void* const* d_in, const int* in_sizes, int n_in,
                              void* d_out, int out_size, void* d_ws, size_t ws_size,
                              hipStream_t stream) {
  const float* z = (const float*)d_in[0];
  float* out = (float*)d_out;
  char* ws = (char*)d_ws;

  // layout: inv_norm 4KB | accum | ... | pbuf 33MB | zb(fp8) 64MB
  float*    inv_norm = (float*)(ws);
  float*    accum    = (float*)(ws + 8192);
  float*    pbuf     = (float*)(ws + 65536);
  uint32_t* zq       = (uint32_t*)(ws + 65536 + (size_t)PARTN * 16384 * sizeof(float));

  hipMemsetAsync(accum, 0, sizeof(float), stream);

  k_prep<<<NROWS, 256, 0, stream>>>(z, zq, inv_norm);

  hipFuncSetAttribute(reinterpret_cast<const void*>(&k_gram8),
                      hipFuncAttributeMaxDynamicSharedMemorySize, 65536);
  k_gram8<<<PARTN, 512, 65536, stream>>>((const unsigned char*)zq, pbuf);

  k_expsum<<<(NROWS * NROWS / 4) / 256, 256, 0, stream>>>(pbuf, inv_norm, accum);
  k_final<<<1, 1, 0, stream>>>(accum, out);
}